// Round 4
// baseline (467.078 us; speedup 1.0000x reference)
//
#include <hip/hip_runtime.h>
#include <hip/hip_bf16.h>
#include <math.h>

// Problem constants
#define BB 32
#define NN 1024
#define DD 2048   // IMG_DIM
#define EE 1024   // EMBED

// ---------------------------------------------------------------------------
// K1a: partial v[b,d] = sum_e cap[b,e] * W1[e,d], split over 16 e-chunks.
// grid: 128 blocks (16 e-chunks x 8 d-slabs), 256 threads.
// ---------------------------------------------------------------------------
__global__ __launch_bounds__(256) void k1_partial(const float* __restrict__ W,
                                                  const float* __restrict__ cap,
                                                  float* __restrict__ part) {
    int ec = blockIdx.x >> 3;        // 0..15
    int dslab = blockIdx.x & 7;      // 0..7
    int d = dslab * 256 + threadIdx.x;
    float acc[BB];
#pragma unroll
    for (int b = 0; b < BB; ++b) acc[b] = 0.f;
    int e0 = ec * 64;
    for (int ee = 0; ee < 64; ++ee) {
        int e = e0 + ee;
        float wv = W[e * DD + d];
#pragma unroll
        for (int b = 0; b < BB; ++b) acc[b] += cap[b * EE + e] * wv;
    }
#pragma unroll
    for (int b = 0; b < BB; ++b) part[(ec * BB + b) * DD + d] = acc[b];
}

// K1b: v = sum of 16 partials.
__global__ __launch_bounds__(256) void k1_reduce(const float* __restrict__ part,
                                                 float* __restrict__ v) {
    int idx = blockIdx.x * 256 + threadIdx.x;  // 0..65535 == b*2048+d
    float s = 0.f;
#pragma unroll
    for (int ec = 0; ec < 16; ++ec) s += part[ec * 65536 + idx];
    v[idx] = s;
}

// ---------------------------------------------------------------------------
// K2: scores[b,n] = images[b,n,:] . v[b,:]   (the 268 MB streaming pass)
// 2048 blocks x 256 threads; each wave owns 4 consecutive rows and keeps
// v[b,:] in 8 float4 registers (rows-per-b=1024 divisible by 4 -> same b).
// ---------------------------------------------------------------------------
__global__ __launch_bounds__(256) void k2_scores(const float4* __restrict__ img4,
                                                 const float4* __restrict__ v4,
                                                 float* __restrict__ scores) {
    int wid = threadIdx.x >> 6;
    int lane = threadIdx.x & 63;
    int w = blockIdx.x * 4 + wid;     // 0..8191
    int r0 = w * 4;                   // first of 4 rows
    int b = r0 >> 10;
    const float4* vp = v4 + b * 512;
    float4 vr[8];
#pragma unroll
    for (int it = 0; it < 8; ++it) vr[it] = vp[it * 64 + lane];
#pragma unroll
    for (int j = 0; j < 4; ++j) {
        const float4* ip = img4 + (size_t)(r0 + j) * 512;
        float acc = 0.f;
#pragma unroll
        for (int it = 0; it < 8; ++it) {
            float4 a = ip[it * 64 + lane];
            acc += a.x * vr[it].x + a.y * vr[it].y + a.z * vr[it].z + a.w * vr[it].w;
        }
#pragma unroll
        for (int off = 32; off > 0; off >>= 1) acc += __shfl_xor(acc, off, 64);
        if (lane == 0) scores[r0 + j] = acc;
    }
}

// ---------------------------------------------------------------------------
// K34: fused masked softmax + compaction (LDS) + u[b,:] accumulation.
// 32 blocks (one per b) x 256 threads.
// ---------------------------------------------------------------------------
__global__ __launch_bounds__(256) void k34(const float* __restrict__ scores,
                                           const int* __restrict__ lengths,
                                           const float* __restrict__ images,
                                           float* __restrict__ wout,
                                           float* __restrict__ u) {
    __shared__ float red[256];
    __shared__ float sw[NN];
    __shared__ int sn[NN];
    __shared__ int scnt;
    int b = blockIdx.x, tid = threadIdx.x;
    int len = lengths[b];
    float s[4];
    bool valid[4];
    float mx = -3.0e38f;
#pragma unroll
    for (int k = 0; k < 4; ++k) {
        int n = tid + k * 256;
        valid[k] = n < len;
        s[k] = valid[k] ? scores[b * NN + n] : -3.0e38f;
        mx = fmaxf(mx, s[k]);
    }
    if (tid == 0) scnt = 0;
    red[tid] = mx;
    __syncthreads();
    for (int o = 128; o > 0; o >>= 1) {
        if (tid < o) red[tid] = fmaxf(red[tid], red[tid + o]);
        __syncthreads();
    }
    mx = red[0];
    __syncthreads();
    float e[4], sum = 0.f;
#pragma unroll
    for (int k = 0; k < 4; ++k) {
        e[k] = valid[k] ? expf(s[k] - mx) : 0.f;
        sum += e[k];
    }
    red[tid] = sum;
    __syncthreads();
    for (int o = 128; o > 0; o >>= 1) {
        if (tid < o) red[tid] += red[tid + o];
        __syncthreads();
    }
    float inv = 1.0f / red[0];
#pragma unroll
    for (int k = 0; k < 4; ++k) {
        int n = tid + k * 256;
        float wv = e[k] * inv;
        wout[b * NN + n] = wv;
        if (wv > 1e-12f) {             // near-one-hot: ~8 survivors/row
            int p = atomicAdd(&scnt, 1);
            sn[p] = n;
            sw[p] = wv;
        }
    }
    __syncthreads();
    int cnt = scnt;
    const float* ib = images + (size_t)b * NN * DD;
#pragma unroll
    for (int c = 0; c < 8; ++c) {
        int d = c * 256 + tid;
        float acc = 0.f;
        for (int i = 0; i < cnt; ++i)
            acc += sw[i] * ib[(size_t)sn[i] * DD + d];
        u[b * DD + d] = acc;
    }
}

// ---------------------------------------------------------------------------
// K5/K6 generic: out[b,e] = x[b,:] . W[e,:] + bias[e]
// One wave per output column e; per-lane acc[32] over batches; wave reduce.
// grid 256 blocks x 256 threads (4 waves -> 1024 e's), nit = rowlen/256.
// ---------------------------------------------------------------------------
__global__ __launch_bounds__(256) void k5_fc(const float4* __restrict__ W4,
                                             const float4* __restrict__ x4,
                                             const float* __restrict__ bias,
                                             float* __restrict__ out, int nit) {
    int wid = threadIdx.x >> 6;
    int lane = threadIdx.x & 63;
    int e = blockIdx.x * 4 + wid;
    int rowq = nit * 64;  // float4s per row
    const float4* wp = W4 + (size_t)e * rowq;
    float acc[BB];
#pragma unroll
    for (int b = 0; b < BB; ++b) acc[b] = 0.f;
    for (int it = 0; it < nit; ++it) {
        float4 wv = wp[it * 64 + lane];
#pragma unroll
        for (int b = 0; b < BB; ++b) {
            float4 uv = x4[b * rowq + it * 64 + lane];
            acc[b] += wv.x * uv.x + wv.y * uv.y + wv.z * uv.z + wv.w * uv.w;
        }
    }
    float bv = bias[e];
#pragma unroll
    for (int b = 0; b < BB; ++b) {
        float r = acc[b];
#pragma unroll
        for (int off = 32; off > 0; off >>= 1) r += __shfl_xor(r, off, 64);
        if (lane == 0) out[b * EE + e] = r + bv;
    }
}

// ---------------------------------------------------------------------------
// K7: l2-normalize each row of fpre -> d_out features region.
// ---------------------------------------------------------------------------
__global__ __launch_bounds__(256) void k7_norm(const float* __restrict__ fpre,
                                               float* __restrict__ outF) {
    __shared__ float red[256];
    int b = blockIdx.x, tid = threadIdx.x;
    float f[4];
    float ss = 0.f;
#pragma unroll
    for (int k = 0; k < 4; ++k) {
        f[k] = fpre[b * EE + tid + k * 256];
        ss += f[k] * f[k];
    }
    red[tid] = ss;
    __syncthreads();
    for (int o = 128; o > 0; o >>= 1) {
        if (tid < o) red[tid] += red[tid + o];
        __syncthreads();
    }
    float inv = 1.0f / sqrtf(red[0]);
#pragma unroll
    for (int k = 0; k < 4; ++k) outF[b * EE + tid + k * 256] = f[k] * inv;
}

extern "C" void kernel_launch(void* const* d_in, const int* in_sizes, int n_in,
                              void* d_out, int out_size, void* d_ws, size_t ws_size,
                              hipStream_t stream) {
    const float* images = (const float*)d_in[0];   // [32,1024,2048]
    const float* cap    = (const float*)d_in[1];   // [32,1024]
    const int*   lens   = (const int*)d_in[2];     // [32]
    const float* ws1_w  = (const float*)d_in[3];   // [1024,2048]
    const float* ws1_b  = (const float*)d_in[4];   // [1024]
    const float* fc_w   = (const float*)d_in[5];   // [1024,1024]
    const float* fc_b   = (const float*)d_in[6];   // [1024]
    float* out = (float*)d_out;                    // features[32*1024] ++ w[32*1024]

    float* wsf    = (float*)d_ws;
    float* part   = wsf;                 // 16*65536 = 1048576 floats (4 MB)
    float* v      = part + 1048576;      // 65536
    float* scores = v + 65536;           // 32768
    float* u      = scores + 32768;      // 65536
    float* fc1    = u + 65536;           // 32768
    float* fpre   = fc1 + 32768;         // 32768
    float* w_out  = out + BB * EE;       // attention weights region of d_out

    k1_partial<<<128, 256, 0, stream>>>(ws1_w, cap, part);
    k1_reduce<<<256, 256, 0, stream>>>(part, v);
    k2_scores<<<2048, 256, 0, stream>>>((const float4*)images, (const float4*)v, scores);
    k34<<<32, 256, 0, stream>>>(scores, lens, images, w_out, u);
    k5_fc<<<256, 256, 0, stream>>>((const float4*)ws1_w, (const float4*)u, ws1_b, fc1, 8);
    k5_fc<<<256, 256, 0, stream>>>((const float4*)fc_w, (const float4*)fc1, fc_b, fpre, 4);
    k7_norm<<<32, 256, 0, stream>>>(fpre, out);
}

// Round 5
// 445.510 us; speedup vs baseline: 1.0484x; 1.0484x over previous
//
#include <hip/hip_runtime.h>
#include <hip/hip_bf16.h>
#include <math.h>

// Problem constants
#define BB 32
#define NN 1024
#define DD 2048   // IMG_DIM
#define EE 1024   // EMBED

// ---------------------------------------------------------------------------
// K1a: partial v[b,d] = sum_e cap[b,e] * W1[e,d], split over 16 e-chunks.
// grid: 128 blocks (16 e-chunks x 8 d-slabs), 256 threads.
// ---------------------------------------------------------------------------
__global__ __launch_bounds__(256) void k1_partial(const float* __restrict__ W,
                                                  const float* __restrict__ cap,
                                                  float* __restrict__ part) {
    int ec = blockIdx.x >> 3;        // 0..15
    int dslab = blockIdx.x & 7;      // 0..7
    int d = dslab * 256 + threadIdx.x;
    float acc[BB];
#pragma unroll
    for (int b = 0; b < BB; ++b) acc[b] = 0.f;
    int e0 = ec * 64;
    for (int ee = 0; ee < 64; ++ee) {
        int e = e0 + ee;
        float wv = W[e * DD + d];
#pragma unroll
        for (int b = 0; b < BB; ++b) acc[b] += cap[b * EE + e] * wv;
    }
#pragma unroll
    for (int b = 0; b < BB; ++b) part[(ec * BB + b) * DD + d] = acc[b];
}

// K1b: v = sum of 16 partials.
__global__ __launch_bounds__(256) void k1_reduce(const float* __restrict__ part,
                                                 float* __restrict__ v) {
    int idx = blockIdx.x * 256 + threadIdx.x;  // 0..65535 == b*2048+d
    float s = 0.f;
#pragma unroll
    for (int ec = 0; ec < 16; ++ec) s += part[ec * 65536 + idx];
    v[idx] = s;
}

// ---------------------------------------------------------------------------
// K2: scores[b,n] = images[b,n,:] . v[b,:]  -- only for n < len[b].
// Rows n >= len[b] are masked downstream (w=0), so their 8 KB image reads
// are dead traffic: skip them (E[len]=768 -> 25% of 268 MB saved).
// One wave per row; 8192 blocks x 256 threads (4 waves).
// ---------------------------------------------------------------------------
__global__ __launch_bounds__(256) void k2_scores(const float4* __restrict__ img4,
                                                 const float4* __restrict__ v4,
                                                 const int* __restrict__ lengths,
                                                 float* __restrict__ scores) {
    int wid = threadIdx.x >> 6;
    int lane = threadIdx.x & 63;
    int r = blockIdx.x * 4 + wid;     // 0..32767  (= b*1024 + n)
    int b = r >> 10;
    int n = r & (NN - 1);
    if (n >= lengths[b]) return;      // masked row: never read, never written
    const float4* ip = img4 + (size_t)r * 512;
    const float4* vp = v4 + b * 512;
    float acc = 0.f;
#pragma unroll
    for (int it = 0; it < 8; ++it) {
        float4 a = ip[it * 64 + lane];
        float4 c = vp[it * 64 + lane];
        acc += a.x * c.x + a.y * c.y + a.z * c.z + a.w * c.w;
    }
#pragma unroll
    for (int off = 32; off > 0; off >>= 1) acc += __shfl_xor(acc, off, 64);
    if (lane == 0) scores[r] = acc;
}

// ---------------------------------------------------------------------------
// K34: fused masked softmax + compaction (LDS) + u[b,:] accumulation.
// 32 blocks (one per b) x 256 threads.
// ---------------------------------------------------------------------------
__global__ __launch_bounds__(256) void k34(const float* __restrict__ scores,
                                           const int* __restrict__ lengths,
                                           const float* __restrict__ images,
                                           float* __restrict__ wout,
                                           float* __restrict__ u) {
    __shared__ float red[256];
    __shared__ float sw[NN];
    __shared__ int sn[NN];
    __shared__ int scnt;
    int b = blockIdx.x, tid = threadIdx.x;
    int len = lengths[b];
    float s[4];
    bool valid[4];
    float mx = -3.0e38f;
#pragma unroll
    for (int k = 0; k < 4; ++k) {
        int n = tid + k * 256;
        valid[k] = n < len;
        s[k] = valid[k] ? scores[b * NN + n] : -3.0e38f;
        mx = fmaxf(mx, s[k]);
    }
    if (tid == 0) scnt = 0;
    red[tid] = mx;
    __syncthreads();
    for (int o = 128; o > 0; o >>= 1) {
        if (tid < o) red[tid] = fmaxf(red[tid], red[tid + o]);
        __syncthreads();
    }
    mx = red[0];
    __syncthreads();
    float e[4], sum = 0.f;
#pragma unroll
    for (int k = 0; k < 4; ++k) {
        e[k] = valid[k] ? expf(s[k] - mx) : 0.f;
        sum += e[k];
    }
    red[tid] = sum;
    __syncthreads();
    for (int o = 128; o > 0; o >>= 1) {
        if (tid < o) red[tid] += red[tid + o];
        __syncthreads();
    }
    float inv = 1.0f / red[0];
#pragma unroll
    for (int k = 0; k < 4; ++k) {
        int n = tid + k * 256;
        float wv = e[k] * inv;
        wout[b * NN + n] = wv;
        if (wv > 1e-12f) {             // near-one-hot: ~8 survivors/row
            int p = atomicAdd(&scnt, 1);
            sn[p] = n;
            sw[p] = wv;
        }
    }
    __syncthreads();
    int cnt = scnt;
    const float* ib = images + (size_t)b * NN * DD;
#pragma unroll
    for (int c = 0; c < 8; ++c) {
        int d = c * 256 + tid;
        float acc = 0.f;
        for (int i = 0; i < cnt; ++i)
            acc += sw[i] * ib[(size_t)sn[i] * DD + d];
        u[b * DD + d] = acc;
    }
}

// ---------------------------------------------------------------------------
// K5/K6 generic: out[b,e] = x[b,:] . W[e,:] + bias[e]
// One wave per output column e; per-lane acc[32] over batches; wave reduce.
// grid 256 blocks x 256 threads (4 waves -> 1024 e's), nit = rowlen/256.
// ---------------------------------------------------------------------------
__global__ __launch_bounds__(256) void k5_fc(const float4* __restrict__ W4,
                                             const float4* __restrict__ x4,
                                             const float* __restrict__ bias,
                                             float* __restrict__ out, int nit) {
    int wid = threadIdx.x >> 6;
    int lane = threadIdx.x & 63;
    int e = blockIdx.x * 4 + wid;
    int rowq = nit * 64;  // float4s per row
    const float4* wp = W4 + (size_t)e * rowq;
    float acc[BB];
#pragma unroll
    for (int b = 0; b < BB; ++b) acc[b] = 0.f;
    for (int it = 0; it < nit; ++it) {
        float4 wv = wp[it * 64 + lane];
#pragma unroll
        for (int b = 0; b < BB; ++b) {
            float4 uv = x4[b * rowq + it * 64 + lane];
            acc[b] += wv.x * uv.x + wv.y * uv.y + wv.z * uv.z + wv.w * uv.w;
        }
    }
    float bv = bias[e];
#pragma unroll
    for (int b = 0; b < BB; ++b) {
        float r = acc[b];
#pragma unroll
        for (int off = 32; off > 0; off >>= 1) r += __shfl_xor(r, off, 64);
        if (lane == 0) out[b * EE + e] = r + bv;
    }
}

// ---------------------------------------------------------------------------
// K7: l2-normalize each row of fpre -> d_out features region.
// ---------------------------------------------------------------------------
__global__ __launch_bounds__(256) void k7_norm(const float* __restrict__ fpre,
                                               float* __restrict__ outF) {
    __shared__ float red[256];
    int b = blockIdx.x, tid = threadIdx.x;
    float f[4];
    float ss = 0.f;
#pragma unroll
    for (int k = 0; k < 4; ++k) {
        f[k] = fpre[b * EE + tid + k * 256];
        ss += f[k] * f[k];
    }
    red[tid] = ss;
    __syncthreads();
    for (int o = 128; o > 0; o >>= 1) {
        if (tid < o) red[tid] += red[tid + o];
        __syncthreads();
    }
    float inv = 1.0f / sqrtf(red[0]);
#pragma unroll
    for (int k = 0; k < 4; ++k) outF[b * EE + tid + k * 256] = f[k] * inv;
}

extern "C" void kernel_launch(void* const* d_in, const int* in_sizes, int n_in,
                              void* d_out, int out_size, void* d_ws, size_t ws_size,
                              hipStream_t stream) {
    const float* images = (const float*)d_in[0];   // [32,1024,2048]
    const float* cap    = (const float*)d_in[1];   // [32,1024]
    const int*   lens   = (const int*)d_in[2];     // [32]
    const float* ws1_w  = (const float*)d_in[3];   // [1024,2048]
    const float* ws1_b  = (const float*)d_in[4];   // [1024]
    const float* fc_w   = (const float*)d_in[5];   // [1024,1024]
    const float* fc_b   = (const float*)d_in[6];   // [1024]
    float* out = (float*)d_out;                    // features[32*1024] ++ w[32*1024]

    float* wsf    = (float*)d_ws;
    float* part   = wsf;                 // 16*65536 = 1048576 floats (4 MB)
    float* v      = part + 1048576;      // 65536
    float* scores = v + 65536;           // 32768
    float* u      = scores + 32768;      // 65536
    float* fc1    = u + 65536;           // 32768
    float* fpre   = fc1 + 32768;         // 32768
    float* w_out  = out + BB * EE;       // attention weights region of d_out

    k1_partial<<<128, 256, 0, stream>>>(ws1_w, cap, part);
    k1_reduce<<<256, 256, 0, stream>>>(part, v);
    k2_scores<<<8192, 256, 0, stream>>>((const float4*)images, (const float4*)v, lens, scores);
    k34<<<32, 256, 0, stream>>>(scores, lens, images, w_out, u);
    k5_fc<<<256, 256, 0, stream>>>((const float4*)ws1_w, (const float4*)u, ws1_b, fc1, 8);
    k5_fc<<<256, 256, 0, stream>>>((const float4*)fc_w, (const float4*)fc1, fc_b, fpre, 4);
    k7_norm<<<32, 256, 0, stream>>>(fpre, out);
}

// Round 6
// 423.647 us; speedup vs baseline: 1.1025x; 1.0516x over previous
//
#include <hip/hip_runtime.h>
#include <hip/hip_bf16.h>
#include <math.h>

// Problem constants
#define BB 32
#define NN 1024
#define DD 2048   // IMG_DIM
#define EE 1024   // EMBED

// ---------------------------------------------------------------------------
// K1a: partial v[b,d] = sum_e cap[b,e] * W1[e,d], split over 16 e-chunks.
// grid: 128 blocks (16 e-chunks x 8 d-slabs), 256 threads.
// ---------------------------------------------------------------------------
__global__ __launch_bounds__(256) void k1_partial(const float* __restrict__ W,
                                                  const float* __restrict__ cap,
                                                  float* __restrict__ part) {
    int ec = blockIdx.x >> 3;        // 0..15
    int dslab = blockIdx.x & 7;      // 0..7
    int d = dslab * 256 + threadIdx.x;
    float acc[BB];
#pragma unroll
    for (int b = 0; b < BB; ++b) acc[b] = 0.f;
    int e0 = ec * 64;
    for (int ee = 0; ee < 64; ++ee) {
        int e = e0 + ee;
        float wv = W[e * DD + d];
#pragma unroll
        for (int b = 0; b < BB; ++b) acc[b] += cap[b * EE + e] * wv;
    }
#pragma unroll
    for (int b = 0; b < BB; ++b) part[(ec * BB + b) * DD + d] = acc[b];
}

// K1b: v = sum of 16 partials.
__global__ __launch_bounds__(256) void k1_reduce(const float* __restrict__ part,
                                                 float* __restrict__ v) {
    int idx = blockIdx.x * 256 + threadIdx.x;  // 0..65535 == b*2048+d
    float s = 0.f;
#pragma unroll
    for (int ec = 0; ec < 16; ++ec) s += part[ec * 65536 + idx];
    v[idx] = s;
}

// ---------------------------------------------------------------------------
// K2: scores[b,n] = images[b,n,:] . v[b,:]  -- only for n < len[b].
// Rows n >= len[b] are masked downstream (w=0): skip their reads entirely.
// One wave per row; 8192 blocks x 256 threads (4 waves).
// ---------------------------------------------------------------------------
__global__ __launch_bounds__(256) void k2_scores(const float4* __restrict__ img4,
                                                 const float4* __restrict__ v4,
                                                 const int* __restrict__ lengths,
                                                 float* __restrict__ scores) {
    int wid = threadIdx.x >> 6;
    int lane = threadIdx.x & 63;
    int r = blockIdx.x * 4 + wid;     // 0..32767  (= b*1024 + n)
    int b = r >> 10;
    int n = r & (NN - 1);
    if (n >= lengths[b]) return;      // masked row: never read, never written
    const float4* ip = img4 + (size_t)r * 512;
    const float4* vp = v4 + b * 512;
    float acc = 0.f;
#pragma unroll
    for (int it = 0; it < 8; ++it) {
        float4 a = ip[it * 64 + lane];
        float4 c = vp[it * 64 + lane];
        acc += a.x * c.x + a.y * c.y + a.z * c.z + a.w * c.w;
    }
#pragma unroll
    for (int off = 32; off > 0; off >>= 1) acc += __shfl_xor(acc, off, 64);
    if (lane == 0) scores[r] = acc;
}

// ---------------------------------------------------------------------------
// K3: masked softmax -> w to d_out + compacted significant (idx,w) list.
// 32 blocks x 256 threads. (~8-16 survivors/row: logits are N(0,~37).)
// ---------------------------------------------------------------------------
__global__ __launch_bounds__(256) void k3_softmax(const float* __restrict__ scores,
                                                  const int* __restrict__ lengths,
                                                  float* __restrict__ wout,
                                                  int* __restrict__ sig_idx,
                                                  float* __restrict__ sig_w,
                                                  int* __restrict__ sig_cnt) {
    __shared__ float red[256];
    __shared__ int scnt;
    int b = blockIdx.x, tid = threadIdx.x;
    int len = lengths[b];
    float s[4];
    bool valid[4];
    float mx = -3.0e38f;
#pragma unroll
    for (int k = 0; k < 4; ++k) {
        int n = tid + k * 256;
        valid[k] = n < len;
        s[k] = valid[k] ? scores[b * NN + n] : -3.0e38f;
        mx = fmaxf(mx, s[k]);
    }
    if (tid == 0) scnt = 0;
    red[tid] = mx;
    __syncthreads();
    for (int o = 128; o > 0; o >>= 1) {
        if (tid < o) red[tid] = fmaxf(red[tid], red[tid + o]);
        __syncthreads();
    }
    mx = red[0];
    __syncthreads();
    float e[4], sum = 0.f;
#pragma unroll
    for (int k = 0; k < 4; ++k) {
        e[k] = valid[k] ? expf(s[k] - mx) : 0.f;
        sum += e[k];
    }
    red[tid] = sum;
    __syncthreads();
    for (int o = 128; o > 0; o >>= 1) {
        if (tid < o) red[tid] += red[tid + o];
        __syncthreads();
    }
    float inv = 1.0f / red[0];
#pragma unroll
    for (int k = 0; k < 4; ++k) {
        int n = tid + k * 256;
        float wv = e[k] * inv;
        wout[b * NN + n] = wv;
        if (wv > 1e-12f) {
            int p = atomicAdd(&scnt, 1);
            sig_idx[b * NN + p] = n;
            sig_w[b * NN + p] = wv;
        }
    }
    __syncthreads();
    if (tid == 0) sig_cnt[b] = scnt;
}

// ---------------------------------------------------------------------------
// K4: u[b,:] = sum over significant rows only (~8-16 per b).
// grid 256 blocks (32 b x 8 d-slabs) x 256 threads.
// ---------------------------------------------------------------------------
__global__ __launch_bounds__(256) void k4_u(const float* __restrict__ images,
                                            const int* __restrict__ sig_idx,
                                            const float* __restrict__ sig_w,
                                            const int* __restrict__ sig_cnt,
                                            float* __restrict__ u) {
    int b = blockIdx.x >> 3;
    int dslab = blockIdx.x & 7;
    int d = dslab * 256 + threadIdx.x;
    int cnt = sig_cnt[b];
    const float* ib = images + (size_t)b * NN * DD;
    float acc = 0.f;
    for (int i = 0; i < cnt; ++i) {
        float wv = sig_w[b * NN + i];
        int n = sig_idx[b * NN + i];
        acc += wv * ib[(size_t)n * DD + d];
    }
    u[b * DD + d] = acc;
}

// ---------------------------------------------------------------------------
// K5/K6 generic: out[b,e] = x[b,:] . W[e,:] + bias[e]
// Two waves per output column e, 16 batches each (2048 waves total for
// latency hiding). grid 512 blocks x 256 threads, nit = rowlen/256.
// ---------------------------------------------------------------------------
__global__ __launch_bounds__(256) void k5_fc(const float4* __restrict__ W4,
                                             const float4* __restrict__ x4,
                                             const float* __restrict__ bias,
                                             float* __restrict__ out, int nit) {
    int w = blockIdx.x * 4 + (threadIdx.x >> 6);  // 0..2047
    int lane = threadIdx.x & 63;
    int e = w >> 1;
    int b0 = (w & 1) * 16;
    int rowq = nit * 64;  // float4s per row
    const float4* wp = W4 + (size_t)e * rowq;
    float acc[16];
#pragma unroll
    for (int j = 0; j < 16; ++j) acc[j] = 0.f;
    for (int it = 0; it < nit; ++it) {
        float4 wv = wp[it * 64 + lane];
#pragma unroll
        for (int j = 0; j < 16; ++j) {
            float4 uv = x4[(size_t)(b0 + j) * rowq + it * 64 + lane];
            acc[j] += wv.x * uv.x + wv.y * uv.y + wv.z * uv.z + wv.w * uv.w;
        }
    }
    float bv = bias[e];
#pragma unroll
    for (int j = 0; j < 16; ++j) {
        float r = acc[j];
#pragma unroll
        for (int off = 32; off > 0; off >>= 1) r += __shfl_xor(r, off, 64);
        if (lane == 0) out[(b0 + j) * EE + e] = r + bv;
    }
}

// ---------------------------------------------------------------------------
// K7: l2-normalize each row of fpre -> d_out features region.
// ---------------------------------------------------------------------------
__global__ __launch_bounds__(256) void k7_norm(const float* __restrict__ fpre,
                                               float* __restrict__ outF) {
    __shared__ float red[256];
    int b = blockIdx.x, tid = threadIdx.x;
    float f[4];
    float ss = 0.f;
#pragma unroll
    for (int k = 0; k < 4; ++k) {
        f[k] = fpre[b * EE + tid + k * 256];
        ss += f[k] * f[k];
    }
    red[tid] = ss;
    __syncthreads();
    for (int o = 128; o > 0; o >>= 1) {
        if (tid < o) red[tid] += red[tid + o];
        __syncthreads();
    }
    float inv = 1.0f / sqrtf(red[0]);
#pragma unroll
    for (int k = 0; k < 4; ++k) outF[b * EE + tid + k * 256] = f[k] * inv;
}

extern "C" void kernel_launch(void* const* d_in, const int* in_sizes, int n_in,
                              void* d_out, int out_size, void* d_ws, size_t ws_size,
                              hipStream_t stream) {
    const float* images = (const float*)d_in[0];   // [32,1024,2048]
    const float* cap    = (const float*)d_in[1];   // [32,1024]
    const int*   lens   = (const int*)d_in[2];     // [32]
    const float* ws1_w  = (const float*)d_in[3];   // [1024,2048]
    const float* ws1_b  = (const float*)d_in[4];   // [1024]
    const float* fc_w   = (const float*)d_in[5];   // [1024,1024]
    const float* fc_b   = (const float*)d_in[6];   // [1024]
    float* out = (float*)d_out;                    // features[32*1024] ++ w[32*1024]

    float* wsf    = (float*)d_ws;
    float* part   = wsf;                 // 16*65536 = 1048576 floats (4 MB)
    float* v      = part + 1048576;      // 65536
    float* scores = v + 65536;           // 32768
    float* u      = scores + 32768;      // 65536
    float* fc1    = u + 65536;           // 32768
    float* fpre   = fc1 + 32768;         // 32768
    float* sig_w  = fpre + 32768;        // 32768
    int*   sig_idx = (int*)(sig_w + 32768);   // 32768
    int*   sig_cnt = sig_idx + 32768;         // 32
    float* w_out  = out + BB * EE;       // attention weights region of d_out

    k1_partial<<<128, 256, 0, stream>>>(ws1_w, cap, part);
    k1_reduce<<<256, 256, 0, stream>>>(part, v);
    k2_scores<<<8192, 256, 0, stream>>>((const float4*)images, (const float4*)v, lens, scores);
    k3_softmax<<<32, 256, 0, stream>>>(scores, lens, w_out, sig_idx, sig_w, sig_cnt);
    k4_u<<<256, 256, 0, stream>>>(images, sig_idx, sig_w, sig_cnt, u);
    k5_fc<<<512, 256, 0, stream>>>((const float4*)ws1_w, (const float4*)u, ws1_b, fc1, 8);
    k5_fc<<<512, 256, 0, stream>>>((const float4*)fc_w, (const float4*)fc1, fc_b, fpre, 4);
    k7_norm<<<32, 256, 0, stream>>>(fpre, out);
}